// Round 12
// baseline (116.420 us; speedup 1.0000x reference)
//
#include <hip/hip_runtime.h>
#include <hip/hip_bf16.h>
#include <stdint.h>

#define NNODES 10000
#define NEDGES 320000
#define DIM    256
#define KTOT   512
#define LN_EPS 1e-5f
#define BCAP   96     // per-node bucket capacity (max degree; P(exceed) ~ 1e-20)

typedef __attribute__((ext_vector_type(4))) float f32x4;
typedef __attribute__((ext_vector_type(8))) short bf16x8;

__device__ __forceinline__ ushort f2bf(float f) {
    union { float f; uint32_t u; } v; v.f = f;
    uint32_t r = v.u + 0x7fffu + ((v.u >> 16) & 1u);   // RNE
    return (ushort)(r >> 16);
}
__device__ __forceinline__ float bf2f(ushort u) {
    union { float f; uint32_t u; } v; v.u = ((uint32_t)u) << 16;
    return v.f;
}

// ---- K1: prep — cast x->bf16, zero cnt, fragment-arrange both W matrices ----
__global__ __launch_bounds__(256)
void prep_all(const float* __restrict__ x, const float* __restrict__ Wm,
              const float* __restrict__ Wu, ushort* __restrict__ xb,
              ushort* __restrict__ Wcat, ushort* __restrict__ Wua,
              int4* __restrict__ cntz) {
    int tid = blockIdx.x * 256 + threadIdx.x;          // 3524*256 = 902144
    if (tid < 2560) cntz[tid] = (int4){0, 0, 0, 0};    // 10240 ints >= NNODES
    if (tid < 640000) {                                // x cast, one float4 each
        float4 v = reinterpret_cast<const float4*>(x)[tid];
        ushort4 o;
        o.x = f2bf(v.x); o.y = f2bf(v.y); o.z = f2bf(v.z); o.w = f2bf(v.w);
        reinterpret_cast<ushort4*>(xb)[tid] = o;
    } else {
        int t = tid - 640000;                          // < 262144
        if (t < 131072) {
            int kk  = t >> 14;
            int rem = t & 16383;
            int g   = rem >> 9;
            int kg  = (rem >> 7) & 3;
            int ml  = (rem >> 3) & 15;
            int j   = rem & 7;
            int k = kk * 32 + kg * 8 + j;
            int n = g * 16 + ml;
            float v = (n < 256) ? Wm[k * DIM + n] : Wm[(k + 256) * DIM + (n - 256)];
            Wcat[t] = f2bf(v);
        } else {
            int rem = t - 131072;
            int kk  = rem >> 13;
            int nt  = (rem >> 9) & 15;
            int kg  = (rem >> 7) & 3;
            int ml  = (rem >> 3) & 15;
            int j   = rem & 7;
            int k = kk * 32 + kg * 8 + j;
            int n = nt * 16 + ml;
            Wua[rem] = f2bf(Wu[k * DIM + n]);
        }
    }
}

// ---- K2: bucket scatter (blocks [0,1250)) ∥ U|V GEMM (blocks [1250,1875)) ----
__global__ __launch_bounds__(256)
void scatter_uv(const int* __restrict__ eidx, int* __restrict__ cnt,
                int* __restrict__ srow, const ushort* __restrict__ xb,
                const ushort* __restrict__ Wcat, const float* __restrict__ bmsg,
                ushort* __restrict__ Ub, float* __restrict__ Vf) {
    if (blockIdx.x < 1250) {
        int e = blockIdx.x * 256 + threadIdx.x;        // 1250*256 = 320000 exact
        int d = eidx[NEDGES + e];
        int p = atomicAdd(&cnt[d], 1);
        if (p < BCAP) srow[d * BCAP + p] = eidx[e];
        return;
    }
    // U = x @ W_msg[:256] (bf16), V = x @ W_msg[256:] + b (fp32)
    const int wq   = threadIdx.x >> 6;
    const int lane = threadIdx.x & 63;
    const int ml = lane & 15, kg = lane >> 4;
    const int nb = (blockIdx.x - 1250) * 16;
    const uint arow = (uint)(nb + ml) * DIM;

    f32x4 acc[8];
#pragma unroll
    for (int nt = 0; nt < 8; ++nt) acc[nt] = (f32x4){0.f, 0.f, 0.f, 0.f};

#pragma unroll
    for (int kk = 0; kk < 8; ++kk) {
        bf16x8 a = *reinterpret_cast<const bf16x8*>(xb + arow + kk * 32 + kg * 8);
#pragma unroll
        for (int nt = 0; nt < 8; ++nt) {
            bf16x8 b = *reinterpret_cast<const bf16x8*>(Wcat + kk * 16384 + (wq * 8 + nt) * 512 + lane * 8);
            acc[nt] = __builtin_amdgcn_mfma_f32_16x16x32_bf16(a, b, acc[nt], 0, 0, 0);
        }
    }

    if (wq < 2) {                                   // U half: bf16
#pragma unroll
        for (int nt = 0; nt < 8; ++nt) {
            const int col = wq * 128 + nt * 16 + ml;
#pragma unroll
            for (int i = 0; i < 4; ++i)
                Ub[(size_t)(nb + kg * 4 + i) * 256 + col] = f2bf(acc[nt][i]);
        }
    } else {                                        // V half: fp32, bias folded
#pragma unroll
        for (int nt = 0; nt < 8; ++nt) {
            const int col = (wq - 2) * 128 + nt * 16 + ml;
            const float bb = bmsg[col];
#pragma unroll
            for (int i = 0; i < 4; ++i)
                Vf[(size_t)(nb + kg * 4 + i) * 256 + col] = acc[nt][i] + bb;
        }
    }
}

// ---- K3: fused edge-combine + node GEMM + LayerNorm ----
// 625 blocks x 512 thr (8 waves) = 16 nodes/block.
// Phase A (balanced): wave w owns cols [w*32, w*32+32) == k-slice kk=w of ALL
//   16 nodes. lane: slot = lane>>3 (8-way edge ILP), cg = lane&7 (4 cols).
//   Per node: reduce slots via shfl_xor(8,16,32); slot-0 lanes write agg frag
//   to LDS in MFMA-fragment order aggB[kk][kg][node][8] -> Phase B reads are
//   lane-linear float4 (zero bank conflicts).
// Phase B: 16x256 update GEMM; k<256 A from xb, k>=256 A from aggB; LN fused.
__global__ __launch_bounds__(512)
void edge_node(const ushort* __restrict__ Ub, const float* __restrict__ Vf,
               const int* __restrict__ srow, const int* __restrict__ cnt,
               const ushort* __restrict__ xb, const ushort* __restrict__ Wua,
               const float* __restrict__ bupd, const float* __restrict__ gamma,
               const float* __restrict__ beta, float* __restrict__ out) {
    __shared__ float aggB[4096];        // [kk][kg][node][8] = 8*4*16*8 = 16 KB
    __shared__ float pS[16][8][2];      // LN partials [node][wave][sum,ssq]

    const int tid  = threadIdx.x;
    const int wave = tid >> 6, lane = tid & 63;
    const int nb = blockIdx.x * 16;
    const int slot = lane >> 3;         // edge slot 0..7
    const int cg   = lane & 7;          // col group (4 cols)
    const int c0   = wave * 32 + cg * 4;

    // ---- Phase A ----
    for (int nn = 0; nn < 16; ++nn) {
        const int d = nb + nn;
        int deg = cnt[d]; deg = deg < BCAP ? deg : BCAP;
        const int beg = d * BCAP;
        const float4 vc = *reinterpret_cast<const float4*>(&Vf[(size_t)d * 256 + c0]);
        float s0 = 0.f, s1 = 0.f, s2 = 0.f, s3 = 0.f;

        const int iters = (deg + 7) >> 3;
        for (int it = 0; it < iters; ++it) {
            const int ei = it * 8 + slot;
            const bool ok = ei < deg;
            const int r = ok ? srow[beg + ei] : 0;     // clamp: poisoned slots unsafe
            ushort4 u = *reinterpret_cast<const ushort4*>(&Ub[(size_t)r * 256 + c0]);
            if (ok) {
                s0 += fmaxf(bf2f(u.x) + vc.x, 0.f);
                s1 += fmaxf(bf2f(u.y) + vc.y, 0.f);
                s2 += fmaxf(bf2f(u.z) + vc.z, 0.f);
                s3 += fmaxf(bf2f(u.w) + vc.w, 0.f);
            }
        }
#pragma unroll
        for (int m = 8; m < 64; m <<= 1) {
            s0 += __shfl_xor(s0, m);
            s1 += __shfl_xor(s1, m);
            s2 += __shfl_xor(s2, m);
            s3 += __shfl_xor(s3, m);
        }
        if (slot == 0) {
            // col c0+j -> kk=wave, kg=cg>>1, j0=(cg&1)*4
            const int idx = wave * 512 + (cg >> 1) * 128 + nn * 8 + (cg & 1) * 4;
            *reinterpret_cast<float4*>(&aggB[idx]) = (float4){s0, s1, s2, s3};
        }
    }
    __syncthreads();

    // ---- Phase B: update GEMM (wave wq owns 32 cols) ----
    const int ml = lane & 15, kg = lane >> 4, wq = wave;
    const uint arow = (uint)(nb + ml) * DIM;

    f32x4 acc[2];
    acc[0] = (f32x4){0.f, 0.f, 0.f, 0.f};
    acc[1] = (f32x4){0.f, 0.f, 0.f, 0.f};

#pragma unroll
    for (int kk = 0; kk < 8; ++kk) {                  // k in [0,256): A = xb
        bf16x8 a = *reinterpret_cast<const bf16x8*>(xb + arow + kk * 32 + kg * 8);
#pragma unroll
        for (int nt = 0; nt < 2; ++nt) {
            bf16x8 b = *reinterpret_cast<const bf16x8*>(Wua + kk * 8192 + (wq * 2 + nt) * 512 + lane * 8);
            acc[nt] = __builtin_amdgcn_mfma_f32_16x16x32_bf16(a, b, acc[nt], 0, 0, 0);
        }
    }
#pragma unroll
    for (int kk = 0; kk < 8; ++kk) {                  // k in [256,512): A = aggB
        const int idx = kk * 512 + kg * 128 + ml * 8;  // lane-linear, conflict-free
        float4 f0 = *reinterpret_cast<const float4*>(&aggB[idx]);
        float4 f1 = *reinterpret_cast<const float4*>(&aggB[idx + 4]);
        union { bf16x8 v; __hip_bfloat162 h2[4]; } u;
        u.h2[0] = __float22bfloat162_rn(make_float2(f0.x, f0.y));
        u.h2[1] = __float22bfloat162_rn(make_float2(f0.z, f0.w));
        u.h2[2] = __float22bfloat162_rn(make_float2(f1.x, f1.y));
        u.h2[3] = __float22bfloat162_rn(make_float2(f1.z, f1.w));
#pragma unroll
        for (int nt = 0; nt < 2; ++nt) {
            bf16x8 b = *reinterpret_cast<const bf16x8*>(Wua + 65536 + kk * 8192 + (wq * 2 + nt) * 512 + lane * 8);
            acc[nt] = __builtin_amdgcn_mfma_f32_16x16x32_bf16(u.v, b, acc[nt], 0, 0, 0);
        }
    }

    // bias + relu + per-wave LN partials (32 cols per wave)
    float sum[4] = {0.f, 0.f, 0.f, 0.f}, ssq[4] = {0.f, 0.f, 0.f, 0.f};
#pragma unroll
    for (int nt = 0; nt < 2; ++nt) {
        const float bb = bupd[(wq * 2 + nt) * 16 + ml];
#pragma unroll
        for (int i = 0; i < 4; ++i) {
            float v = acc[nt][i] + bb;
            v = v > 0.f ? v : 0.f;
            acc[nt][i] = v;
            sum[i] += v;
            ssq[i] += v * v;
        }
    }
#pragma unroll
    for (int m = 1; m < 16; m <<= 1) {
#pragma unroll
        for (int i = 0; i < 4; ++i) {
            sum[i] += __shfl_xor(sum[i], m);
            ssq[i] += __shfl_xor(ssq[i], m);
        }
    }
    if (ml == 0) {
#pragma unroll
        for (int i = 0; i < 4; ++i) {
            pS[kg * 4 + i][wq][0] = sum[i];
            pS[kg * 4 + i][wq][1] = ssq[i];
        }
    }
    __syncthreads();

    float mu[4], rs[4];
#pragma unroll
    for (int i = 0; i < 4; ++i) {
        int r = kg * 4 + i;
        float S = 0.f, Q = 0.f;
#pragma unroll
        for (int w = 0; w < 8; ++w) { S += pS[r][w][0]; Q += pS[r][w][1]; }
        float m = S * (1.f / 256.f);
        float var = Q * (1.f / 256.f) - m * m;
        mu[i] = m;
        rs[i] = rsqrtf(var + LN_EPS);
    }
#pragma unroll
    for (int nt = 0; nt < 2; ++nt) {
        const int cc = (wq * 2 + nt) * 16 + ml;
        const float g = gamma[cc], be = beta[cc];
#pragma unroll
        for (int i = 0; i < 4; ++i) {
            const int node = nb + kg * 4 + i;
            out[(size_t)node * DIM + cc] = (acc[nt][i] - mu[i]) * rs[i] * g + be;
        }
    }
}

extern "C" void kernel_launch(void* const* d_in, const int* in_sizes, int n_in,
                              void* d_out, int out_size, void* d_ws, size_t ws_size,
                              hipStream_t stream) {
    const float* x    = (const float*)d_in[0];
    const int*   eidx = (const int*)  d_in[1];
    const float* Wm   = (const float*)d_in[2];
    const float* bm   = (const float*)d_in[3];
    const float* Wu   = (const float*)d_in[4];
    const float* bu   = (const float*)d_in[5];
    const float* gam  = (const float*)d_in[6];
    const float* bet  = (const float*)d_in[7];
    float* out = (float*)d_out;

    char* ws = (char*)d_ws;
    ushort* xb     = (ushort*)(ws);                    //  5,120,000 B
    ushort* Ub     = (ushort*)(ws +  5120000);         //  5,120,000 B
    float*  Vf     = (float*) (ws + 10240000);         // 10,240,000 B
    ushort* Wcat   = (ushort*)(ws + 20480000);         //    262,144 B
    ushort* Wua    = (ushort*)(ws + 20742144);         //    262,144 B
    int*    cnt    = (int*)   (ws + 21004288);         //     40,960 B
    int*    srow   = (int*)   (ws + 21045248);         //  3,840,000 B (end ~24.9 MB)

    prep_all<<<3524, 256, 0, stream>>>(x, Wm, Wu, xb, Wcat, Wua, (int4*)cnt);
    scatter_uv<<<1875, 256, 0, stream>>>(eidx, cnt, srow, xb, Wcat, bm, Ub, Vf);
    edge_node<<<625, 512, 0, stream>>>(Ub, Vf, srow, cnt, xb, Wua, bu, gam, bet, out);
}

// Round 13
// 83.546 us; speedup vs baseline: 1.3935x; 1.3935x over previous
//
#include <hip/hip_runtime.h>
#include <hip/hip_bf16.h>
#include <stdint.h>

#define NNODES 10000
#define NEDGES 320000
#define DIM    256
#define KTOT   512
#define LN_EPS 1e-5f
#define BCAP   96     // per-node bucket capacity (max degree; P(exceed) ~ 1e-20)

typedef __attribute__((ext_vector_type(4))) float f32x4;
typedef __attribute__((ext_vector_type(8))) short bf16x8;

__device__ __forceinline__ ushort f2bf(float f) {
    union { float f; uint32_t u; } v; v.f = f;
    uint32_t r = v.u + 0x7fffu + ((v.u >> 16) & 1u);   // RNE
    return (ushort)(r >> 16);
}
__device__ __forceinline__ float bf2f(ushort u) {
    union { float f; uint32_t u; } v; v.u = ((uint32_t)u) << 16;
    return v.f;
}

// ---- K1: prep — cast x->bf16, zero cnt, fragment-arrange both W matrices ----
__global__ __launch_bounds__(256)
void prep_all(const float* __restrict__ x, const float* __restrict__ Wm,
              const float* __restrict__ Wu, ushort* __restrict__ xb,
              ushort* __restrict__ Wcat, ushort* __restrict__ Wua,
              int4* __restrict__ cntz) {
    int tid = blockIdx.x * 256 + threadIdx.x;          // 3524*256 = 902144
    if (tid < 2560) cntz[tid] = (int4){0, 0, 0, 0};    // 10240 ints >= NNODES
    if (tid < 640000) {                                // x cast, one float4 each
        float4 v = reinterpret_cast<const float4*>(x)[tid];
        ushort4 o;
        o.x = f2bf(v.x); o.y = f2bf(v.y); o.z = f2bf(v.z); o.w = f2bf(v.w);
        reinterpret_cast<ushort4*>(xb)[tid] = o;
    } else {
        int t = tid - 640000;                          // < 262144
        if (t < 131072) {
            int kk  = t >> 14;
            int rem = t & 16383;
            int g   = rem >> 9;
            int kg  = (rem >> 7) & 3;
            int ml  = (rem >> 3) & 15;
            int j   = rem & 7;
            int k = kk * 32 + kg * 8 + j;
            int n = g * 16 + ml;
            float v = (n < 256) ? Wm[k * DIM + n] : Wm[(k + 256) * DIM + (n - 256)];
            Wcat[t] = f2bf(v);
        } else {
            int rem = t - 131072;
            int kk  = rem >> 13;
            int nt  = (rem >> 9) & 15;
            int kg  = (rem >> 7) & 3;
            int ml  = (rem >> 3) & 15;
            int j   = rem & 7;
            int k = kk * 32 + kg * 8 + j;
            int n = nt * 16 + ml;
            Wua[rem] = f2bf(Wu[k * DIM + n]);
        }
    }
}

// ---- K2: bucket scatter (blocks [0,1250)) ∥ U|V GEMM (blocks [1250,1875)) ----
__global__ __launch_bounds__(256)
void scatter_uv(const int* __restrict__ eidx, int* __restrict__ cnt,
                int* __restrict__ srow, const ushort* __restrict__ xb,
                const ushort* __restrict__ Wcat, const float* __restrict__ bmsg,
                ushort* __restrict__ Ub, float* __restrict__ Vf) {
    if (blockIdx.x < 1250) {
        int e = blockIdx.x * 256 + threadIdx.x;        // 1250*256 = 320000 exact
        int d = eidx[NEDGES + e];
        int p = atomicAdd(&cnt[d], 1);
        if (p < BCAP) srow[d * BCAP + p] = eidx[e];
        return;
    }
    // U = x @ W_msg[:256] (bf16), V = x @ W_msg[256:] + b (fp32)
    const int wq   = threadIdx.x >> 6;
    const int lane = threadIdx.x & 63;
    const int ml = lane & 15, kg = lane >> 4;
    const int nb = (blockIdx.x - 1250) * 16;
    const uint arow = (uint)(nb + ml) * DIM;

    f32x4 acc[8];
#pragma unroll
    for (int nt = 0; nt < 8; ++nt) acc[nt] = (f32x4){0.f, 0.f, 0.f, 0.f};

#pragma unroll
    for (int kk = 0; kk < 8; ++kk) {
        bf16x8 a = *reinterpret_cast<const bf16x8*>(xb + arow + kk * 32 + kg * 8);
#pragma unroll
        for (int nt = 0; nt < 8; ++nt) {
            bf16x8 b = *reinterpret_cast<const bf16x8*>(Wcat + kk * 16384 + (wq * 8 + nt) * 512 + lane * 8);
            acc[nt] = __builtin_amdgcn_mfma_f32_16x16x32_bf16(a, b, acc[nt], 0, 0, 0);
        }
    }

    if (wq < 2) {                                   // U half: bf16
#pragma unroll
        for (int nt = 0; nt < 8; ++nt) {
            const int col = wq * 128 + nt * 16 + ml;
#pragma unroll
            for (int i = 0; i < 4; ++i)
                Ub[(size_t)(nb + kg * 4 + i) * 256 + col] = f2bf(acc[nt][i]);
        }
    } else {                                        // V half: fp32, bias folded
#pragma unroll
        for (int nt = 0; nt < 8; ++nt) {
            const int col = (wq - 2) * 128 + nt * 16 + ml;
            const float bb = bmsg[col];
#pragma unroll
            for (int i = 0; i < 4; ++i)
                Vf[(size_t)(nb + kg * 4 + i) * 256 + col] = acc[nt][i] + bb;
        }
    }
}

// ---- K3: fused edge-combine + node GEMM + LayerNorm ----
// 1250 blocks x 256 thr (4 waves) = 8 nodes/block (4.9 blocks/CU: kills the
// R11 grid-quantization tail).
// Phase A (R11-proven shape): wave w reduces nodes nb+2w, nb+2w+1; lane owns
//   8 cols (16B U loads); 32-lane halves split edges by parity; one
//   shfl_xor(32) combine; agg row -> LDS aggS[8][260].
// Then the k<256 GEMM half runs BEFORE __syncthreads (no aggS dependency) so
// early waves overlap the slowest wave's Phase A. After the barrier: k>=256
// from aggS (rows ml&7), then fused LN. A-rows 8..15 duplicate 0..7; writes
// guarded kg<2.
__global__ __launch_bounds__(256)
void edge_node(const ushort* __restrict__ Ub, const float* __restrict__ Vf,
               const int* __restrict__ srow, const int* __restrict__ cnt,
               const ushort* __restrict__ xb, const ushort* __restrict__ Wua,
               const float* __restrict__ bupd, const float* __restrict__ gamma,
               const float* __restrict__ beta, float* __restrict__ out) {
    __shared__ float aggS[8][260];      // +4 pad
    __shared__ float pS[16][4][2];      // LN partials [row][wave][sum,ssq]

    const int tid  = threadIdx.x;
    const int wave = tid >> 6, lane = tid & 63;
    const int nb = blockIdx.x * 8;
    const int el = lane >> 5;           // half id (edge-parity)
    const int cl = lane & 31;
    const int c0 = cl * 8;              // 8 cols owned

    // ---- Phase A ----
#pragma unroll
    for (int nn = 0; nn < 2; ++nn) {
        const int d = nb + wave * 2 + nn;
        int deg = cnt[d]; deg = deg < BCAP ? deg : BCAP;
        const int beg = d * BCAP;
        const float4 va = *reinterpret_cast<const float4*>(&Vf[(size_t)d * 256 + c0]);
        const float4 vb = *reinterpret_cast<const float4*>(&Vf[(size_t)d * 256 + c0 + 4]);
        float s[8];
#pragma unroll
        for (int j = 0; j < 8; ++j) s[j] = 0.f;

#define ACC8(U) do { \
        s[0] += fmaxf(bf2f((ushort)(U)[0]) + va.x, 0.f); \
        s[1] += fmaxf(bf2f((ushort)(U)[1]) + va.y, 0.f); \
        s[2] += fmaxf(bf2f((ushort)(U)[2]) + va.z, 0.f); \
        s[3] += fmaxf(bf2f((ushort)(U)[3]) + va.w, 0.f); \
        s[4] += fmaxf(bf2f((ushort)(U)[4]) + vb.x, 0.f); \
        s[5] += fmaxf(bf2f((ushort)(U)[5]) + vb.y, 0.f); \
        s[6] += fmaxf(bf2f((ushort)(U)[6]) + vb.z, 0.f); \
        s[7] += fmaxf(bf2f((ushort)(U)[7]) + vb.w, 0.f); } while (0)

        int i = el;                      // this half handles indices el, el+2, ...
        for (; i + 6 < deg; i += 8) {    // 4 rows in flight per half
            int r0 = srow[beg + i],     r1 = srow[beg + i + 2];
            int r2 = srow[beg + i + 4], r3 = srow[beg + i + 6];
            bf16x8 u0 = *reinterpret_cast<const bf16x8*>(&Ub[(size_t)r0 * 256 + c0]);
            bf16x8 u1 = *reinterpret_cast<const bf16x8*>(&Ub[(size_t)r1 * 256 + c0]);
            bf16x8 u2 = *reinterpret_cast<const bf16x8*>(&Ub[(size_t)r2 * 256 + c0]);
            bf16x8 u3 = *reinterpret_cast<const bf16x8*>(&Ub[(size_t)r3 * 256 + c0]);
            ACC8(u0); ACC8(u1); ACC8(u2); ACC8(u3);
        }
        for (; i < deg; i += 2) {
            int r = srow[beg + i];
            bf16x8 u = *reinterpret_cast<const bf16x8*>(&Ub[(size_t)r * 256 + c0]);
            ACC8(u);
        }
#undef ACC8
#pragma unroll
        for (int j = 0; j < 8; ++j) s[j] += __shfl_xor(s[j], 32);
        if (el == 0) {
            *reinterpret_cast<float4*>(&aggS[wave * 2 + nn][c0])     = (float4){s[0], s[1], s[2], s[3]};
            *reinterpret_cast<float4*>(&aggS[wave * 2 + nn][c0 + 4]) = (float4){s[4], s[5], s[6], s[7]};
        }
    }

    // ---- Phase B, k<256 half (independent of aggS -> before barrier) ----
    const int ml = lane & 15, kg = lane >> 4, wq = wave;
    const uint arow = (uint)(nb + (ml & 7)) * DIM;    // rows 8..15 duplicate 0..7

    f32x4 acc[4];
#pragma unroll
    for (int nt = 0; nt < 4; ++nt) acc[nt] = (f32x4){0.f, 0.f, 0.f, 0.f};

#pragma unroll
    for (int kk = 0; kk < 8; ++kk) {
        bf16x8 a = *reinterpret_cast<const bf16x8*>(xb + arow + kk * 32 + kg * 8);
#pragma unroll
        for (int nt = 0; nt < 4; ++nt) {
            bf16x8 b = *reinterpret_cast<const bf16x8*>(Wua + kk * 8192 + (wq * 4 + nt) * 512 + lane * 8);
            acc[nt] = __builtin_amdgcn_mfma_f32_16x16x32_bf16(a, b, acc[nt], 0, 0, 0);
        }
    }
    __syncthreads();

    // ---- Phase B, k>=256 half: A from aggS ----
#pragma unroll
    for (int kk = 0; kk < 8; ++kk) {
        float4 f0 = *reinterpret_cast<const float4*>(&aggS[ml & 7][kk * 32 + kg * 8]);
        float4 f1 = *reinterpret_cast<const float4*>(&aggS[ml & 7][kk * 32 + kg * 8 + 4]);
        union { bf16x8 v; __hip_bfloat162 h2[4]; } u;
        u.h2[0] = __float22bfloat162_rn(make_float2(f0.x, f0.y));
        u.h2[1] = __float22bfloat162_rn(make_float2(f0.z, f0.w));
        u.h2[2] = __float22bfloat162_rn(make_float2(f1.x, f1.y));
        u.h2[3] = __float22bfloat162_rn(make_float2(f1.z, f1.w));
#pragma unroll
        for (int nt = 0; nt < 4; ++nt) {
            bf16x8 b = *reinterpret_cast<const bf16x8*>(Wua + 65536 + kk * 8192 + (wq * 4 + nt) * 512 + lane * 8);
            acc[nt] = __builtin_amdgcn_mfma_f32_16x16x32_bf16(u.v, b, acc[nt], 0, 0, 0);
        }
    }

    // bias + relu + per-wave LN partials (64 cols per wave)
    float sum[4] = {0.f, 0.f, 0.f, 0.f}, ssq[4] = {0.f, 0.f, 0.f, 0.f};
#pragma unroll
    for (int nt = 0; nt < 4; ++nt) {
        const float bb = bupd[(wq * 4 + nt) * 16 + ml];
#pragma unroll
        for (int i = 0; i < 4; ++i) {
            float v = acc[nt][i] + bb;
            v = v > 0.f ? v : 0.f;
            acc[nt][i] = v;
            sum[i] += v;
            ssq[i] += v * v;
        }
    }
#pragma unroll
    for (int m = 1; m < 16; m <<= 1) {
#pragma unroll
        for (int i = 0; i < 4; ++i) {
            sum[i] += __shfl_xor(sum[i], m);
            ssq[i] += __shfl_xor(ssq[i], m);
        }
    }
    if (ml == 0) {
#pragma unroll
        for (int i = 0; i < 4; ++i) {
            pS[kg * 4 + i][wq][0] = sum[i];
            pS[kg * 4 + i][wq][1] = ssq[i];
        }
    }
    __syncthreads();

    float mu[4], rs[4];
#pragma unroll
    for (int i = 0; i < 4; ++i) {
        int r = kg * 4 + i;
        float S = 0.f, Q = 0.f;
#pragma unroll
        for (int w = 0; w < 4; ++w) { S += pS[r][w][0]; Q += pS[r][w][1]; }
        float m = S * (1.f / 256.f);
        float var = Q * (1.f / 256.f) - m * m;
        mu[i] = m;
        rs[i] = rsqrtf(var + LN_EPS);
    }
    if (kg < 2) {                                     // rows 0..7 = real nodes
#pragma unroll
        for (int nt = 0; nt < 4; ++nt) {
            const int cc = (wq * 4 + nt) * 16 + ml;
            const float g = gamma[cc], be = beta[cc];
#pragma unroll
            for (int i = 0; i < 4; ++i) {
                const int node = nb + kg * 4 + i;
                out[(size_t)node * DIM + cc] = (acc[nt][i] - mu[i]) * rs[i] * g + be;
            }
        }
    }
}

extern "C" void kernel_launch(void* const* d_in, const int* in_sizes, int n_in,
                              void* d_out, int out_size, void* d_ws, size_t ws_size,
                              hipStream_t stream) {
    const float* x    = (const float*)d_in[0];
    const int*   eidx = (const int*)  d_in[1];
    const float* Wm   = (const float*)d_in[2];
    const float* bm   = (const float*)d_in[3];
    const float* Wu   = (const float*)d_in[4];
    const float* bu   = (const float*)d_in[5];
    const float* gam  = (const float*)d_in[6];
    const float* bet  = (const float*)d_in[7];
    float* out = (float*)d_out;

    char* ws = (char*)d_ws;
    ushort* xb     = (ushort*)(ws);                    //  5,120,000 B
    ushort* Ub     = (ushort*)(ws +  5120000);         //  5,120,000 B
    float*  Vf     = (float*) (ws + 10240000);         // 10,240,000 B
    ushort* Wcat   = (ushort*)(ws + 20480000);         //    262,144 B
    ushort* Wua    = (ushort*)(ws + 20742144);         //    262,144 B
    int*    cnt    = (int*)   (ws + 21004288);         //     40,960 B
    int*    srow   = (int*)   (ws + 21045248);         //  3,840,000 B (end ~24.9 MB)

    prep_all<<<3524, 256, 0, stream>>>(x, Wm, Wu, xb, Wcat, Wua, (int4*)cnt);
    scatter_uv<<<1875, 256, 0, stream>>>(eidx, cnt, srow, xb, Wcat, bm, Ub, Vf);
    edge_node<<<NNODES / 8, 256, 0, stream>>>(Ub, Vf, srow, cnt, xb, Wua, bu, gam, bet, out);
}